// Round 10
// baseline (67.581 us; speedup 1.0000x reference)
//
#include <hip/hip_runtime.h>
#include <hip/hip_bf16.h>
#include <float.h>

#define B 16
#define H 32
#define HKV 8
#define HP 4            // kv-head pairs
#define G 4
#define D 128
#define LMAX 2048
#define SCALE 0.08838834764831844f  // 1/sqrt(128)

// Kernel 1: ONE WAVE per (b, kv-head-PAIR, split). The pair's slice of a slot
// row is 1KB CONTIGUOUS -> one wave-load (64 lanes x 16B, lane t reads floats
// [t*4, t*4+4)) = one full DRAM page per request. Half-wave hw owns head
// 2hp+hw (its 128 floats are lanes hw*32..hw*32+31). QK = 16 FMA + width-32
// butterfly; softmax fully in-wave; PV symmetric. No barriers, no inter-wave
// coupling; tails handled branchlessly (clamped loads, p=0).
// part_o : [B][HKV][NSPLIT][G][D]  (written only if split non-empty)
// part_ml: [B][HKV][NSPLIT][G][2]  (m, sum_exp; always written)
template <int CHUNK>
__global__ __launch_bounds__(64, 2) void attn_partial(
    const float* __restrict__ q,
    const float* __restrict__ kin,
    const float* __restrict__ vin,
    const float* __restrict__ kc,
    const float* __restrict__ vc,
    const int*  __restrict__ slot_mapping,
    const int*  __restrict__ active_slots,
    const int*  __restrict__ context_lens,
    float* __restrict__ part_o,
    float* __restrict__ part_ml)
{
    constexpr int NSPLIT = LMAX / CHUNK;
    const int tid   = threadIdx.x;            // 0..63
    const int split = blockIdx.x % NSPLIT;
    const int hp    = (blockIdx.x / NSPLIT) % HP;
    const int b     = blockIdx.x / (NSPLIT * HP);

    const int ctx   = context_lens[b];
    const int start = split * CHUNK;
    int nvalid = ctx - start;
    if (nvalid > CHUNK) nvalid = CHUNK;

    if (nvalid <= 0) {
        if (tid < 16) {
            const int hh = hp * 2 + (tid >> 3), g = (tid >> 1) & 3, w = tid & 1;
            part_ml[(((size_t)(b * HKV + hh) * NSPLIT + split) * G + g) * 2 + w] =
                w ? 0.f : -FLT_MAX;
        }
        return;
    }

    __shared__ const float* kbs[CHUNK];   // wave-private (1 wave/block)
    __shared__ const float* vbs[CHUNK];
    __shared__ float4 sc4[CHUNK][2];      // [slot][head-of-pair] scores, then p
    float* scf = (float*)&sc4[0][0];

    // ---- resolve slot -> 1KB pair-slice base pointers (slot_mapping uniform -> s_loads)
    for (int li = tid; li < nvalid; li += 64) {
        const int s = active_slots[b * LMAX + start + li];
        int ov = -1;
#pragma unroll
        for (int j = 0; j < 16; ++j)
            if (slot_mapping[j] == s) ov = j;
        const size_t off = (size_t)(hp * 2) * D;
        kbs[li] = ((ov >= 0) ? kin + (size_t)ov * (HKV * D) : kc + (size_t)s * (HKV * D)) + off;
        vbs[li] = ((ov >= 0) ? vin + (size_t)ov * (HKV * D) : vc + (size_t)s * (HKV * D)) + off;
    }

    const int hw = tid >> 5;        // head within pair (half-wave)
    const int dl = tid & 31;        // d-chunk within head
    const int h  = hp * 2 + hw;

    // q fragments (pre-scaled): qv[g] = floats [dl*4, dl*4+4) of q-head h*G+g
    float4 qv[G];
#pragma unroll
    for (int g = 0; g < G; ++g) {
        float4 t = *(const float4*)(q + ((size_t)(b * H + h * G + g)) * D + dl * 4);
        qv[g] = make_float4(t.x * SCALE, t.y * SCALE, t.z * SCALE, t.w * SCALE);
    }

    const int rmax = (nvalid + 3) & ~3;

    // ---- QK: one 1KB contiguous wave-load per slot (lane t -> floats t*4..);
    //      half-wave hw thus holds head hw's 128 floats; width-32 butterfly
#pragma unroll 4
    for (int r = 0; r < rmax; ++r) {
        const int rl = (r < nvalid) ? r : nvalid - 1;     // branchless clamp
        const float4 kv = *(const float4*)(kbs[rl] + tid * 4);
        float pd0 = kv.x * qv[0].x + kv.y * qv[0].y + kv.z * qv[0].z + kv.w * qv[0].w;
        float pd1 = kv.x * qv[1].x + kv.y * qv[1].y + kv.z * qv[1].z + kv.w * qv[1].w;
        float pd2 = kv.x * qv[2].x + kv.y * qv[2].y + kv.z * qv[2].z + kv.w * qv[2].w;
        float pd3 = kv.x * qv[3].x + kv.y * qv[3].y + kv.z * qv[3].z + kv.w * qv[3].w;
#pragma unroll
        for (int msk = 1; msk < 32; msk <<= 1) {
            pd0 += __shfl_xor(pd0, msk, 32);
            pd1 += __shfl_xor(pd1, msk, 32);
            pd2 += __shfl_xor(pd2, msk, 32);
            pd3 += __shfl_xor(pd3, msk, 32);
        }
        if (dl == 0) sc4[r][hw] = make_float4(pd0, pd1, pd2, pd3);
    }

    // ---- softmax in-wave: 8 rows (2 heads x 4 g) x 8 lanes each
    {
        const int r8  = tid >> 3;        // row: head (r8>>2), g (r8&3)
        const int off = tid & 7;
        const int hw2 = r8 >> 2, g = r8 & 3;
        float m = -FLT_MAX;
        for (int i = off; i < nvalid; i += 8) m = fmaxf(m, scf[(i * 2 + hw2) * 4 + g]);
#pragma unroll
        for (int msk = 1; msk < 8; msk <<= 1) m = fmaxf(m, __shfl_xor(m, msk, 8));
        float sum = 0.f;
        for (int i = off; i < rmax; i += 8) {
            const float p = (i < nvalid) ? __expf(scf[(i * 2 + hw2) * 4 + g] - m) : 0.f;
            scf[(i * 2 + hw2) * 4 + g] = p;
            sum += p;
        }
#pragma unroll
        for (int msk = 1; msk < 8; msk <<= 1) sum += __shfl_xor(sum, msk, 8);
        if (off == 0) {
            const size_t mlb =
                (((size_t)(b * HKV + hp * 2 + hw2) * NSPLIT + split) * G + g) * 2;
            part_ml[mlb + 0] = m;
            part_ml[mlb + 1] = sum;
        }
    }

    // ---- PV: one 1KB contiguous wave-load per slot; broadcast p float4
    float4 a0 = {0,0,0,0}, a1 = {0,0,0,0}, a2 = {0,0,0,0}, a3 = {0,0,0,0};
#pragma unroll 4
    for (int r = 0; r < rmax; ++r) {
        const int rl = (r < nvalid) ? r : nvalid - 1;
        const float4 vv = *(const float4*)(vbs[rl] + tid * 4);
        const float4 p4 = sc4[r][hw];     // p=0 beyond nvalid
        a0.x += p4.x * vv.x; a0.y += p4.x * vv.y; a0.z += p4.x * vv.z; a0.w += p4.x * vv.w;
        a1.x += p4.y * vv.x; a1.y += p4.y * vv.y; a1.z += p4.y * vv.z; a1.w += p4.y * vv.w;
        a2.x += p4.z * vv.x; a2.y += p4.z * vv.y; a2.z += p4.z * vv.z; a2.w += p4.z * vv.w;
        a3.x += p4.w * vv.x; a3.y += p4.w * vv.y; a3.z += p4.w * vv.z; a3.w += p4.w * vv.w;
    }
    {
        const size_t ob = ((size_t)(b * HKV + h) * NSPLIT + split) * G;
        *(float4*)(part_o + (ob + 0) * D + dl * 4) = a0;
        *(float4*)(part_o + (ob + 1) * D + dl * 4) = a1;
        *(float4*)(part_o + (ob + 2) * D + dl * 4) = a2;
        *(float4*)(part_o + (ob + 3) * D + dl * 4) = a3;
    }
}

// Kernel 2: merge nsplit partials per (b, h, g); 2-way split-parallel.
__global__ __launch_bounds__(256) void attn_reduce(
    const float* __restrict__ part_o,
    const float* __restrict__ part_ml,
    float* __restrict__ out,
    int nsplit)
{
    const int g = blockIdx.x & 3;
    const int h = (blockIdx.x >> 2) & 7;
    const int b = blockIdx.x >> 5;
    const int d  = threadIdx.x & 127;
    const int sp = threadIdx.x >> 7;

    __shared__ float mlds[64], llds[64];
    __shared__ float red[128];
    __shared__ float lred;
    const size_t base = (size_t)(b * HKV + h) * nsplit;

    for (int s = threadIdx.x; s < nsplit; s += 256) {
        mlds[s] = part_ml[((base + s) * G + g) * 2 + 0];
        llds[s] = part_ml[((base + s) * G + g) * 2 + 1];
    }
    __syncthreads();

    float M = -FLT_MAX;
    for (int s = 0; s < nsplit; ++s)
        if (llds[s] > 0.f) M = fmaxf(M, mlds[s]);

    float L = 0.f, acc = 0.f;
    for (int s = sp; s < nsplit; s += 2) {
        const float l = llds[s];
        if (l > 0.f) {
            const float e = __expf(mlds[s] - M);
            L += l * e;
            acc += e * part_o[((base + s) * G + g) * D + d];
        }
    }
    if (sp == 1) {
        red[d] = acc;
        if (d == 0) lred = L;
    }
    __syncthreads();
    if (sp == 0) {
        acc += red[d];
        L   += lred;
        out[((size_t)(b * H) + h * G + g) * D + d] = acc / (L > 0.f ? L : 1.f);
    }
}

extern "C" void kernel_launch(void* const* d_in, const int* in_sizes, int n_in,
                              void* d_out, int out_size, void* d_ws, size_t ws_size,
                              hipStream_t stream) {
    const float* q  = (const float*)d_in[0];
    const float* k  = (const float*)d_in[1];
    const float* v  = (const float*)d_in[2];
    const float* kc = (const float*)d_in[3];
    const float* vc = (const float*)d_in[4];
    const int* slot_mapping = (const int*)d_in[5];
    const int* active_slots = (const int*)d_in[6];
    const int* context_lens = (const int*)d_in[7];
    float* out = (float*)d_out;

    const size_t perSplit = (size_t)B * HKV * (G * D + G * 2) * sizeof(float);
    int nsplit = 8;
    if (ws_size >= 32 * perSplit)      nsplit = 32;
    else if (ws_size >= 16 * perSplit) nsplit = 16;

    float* part_o  = (float*)d_ws;
    float* part_ml = part_o + (size_t)B * HKV * nsplit * G * D;

    if (nsplit == 32) {
        attn_partial<64><<<B * HP * 32, 64, 0, stream>>>(
            q, k, v, kc, vc, slot_mapping, active_slots, context_lens, part_o, part_ml);
    } else if (nsplit == 16) {
        attn_partial<128><<<B * HP * 16, 64, 0, stream>>>(
            q, k, v, kc, vc, slot_mapping, active_slots, context_lens, part_o, part_ml);
    } else {
        attn_partial<256><<<B * HP * 8, 64, 0, stream>>>(
            q, k, v, kc, vc, slot_mapping, active_slots, context_lens, part_o, part_ml);
    }
    attn_reduce<<<B * HKV * G, 256, 0, stream>>>(part_o, part_ml, out, nsplit);
}

// Round 11
// 42.088 us; speedup vs baseline: 1.6057x; 1.6057x over previous
//
#include <hip/hip_runtime.h>
#include <hip/hip_bf16.h>
#include <float.h>

#define B 16
#define H 32
#define HKV 8
#define G 4
#define D 128
#define LMAX 2048
#define SCALE 0.08838834764831844f  // 1/sqrt(128)
#define THR 8.0f                    // defer-max rescale threshold (T13)

// Kernel 1: ONE WAVE per (b, kv-head, split), SINGLE PASS over slots with
// per-group online softmax. 8 groups x 8 lanes; group g processes rows
// it*8+g. Per row: K row (4x float4/lane) AND V row (4x float4/lane) issued
// together -> 8 loads in flight; dot + width-8 butterfly; running (m,l,O)
// in registers with defer-max (rescale only when s > m+8, ~never). Epilogue
// merges the 8 groups' partials via LDS (single wave -> no barriers).
// part_o : [B][HKV][NSPLIT][G][D]  (written only if split non-empty)
// part_ml: [B][HKV][NSPLIT][G][2]  (m, sum_exp; always written)
template <int CHUNK>
__global__ __launch_bounds__(64) void attn_partial(
    const float* __restrict__ q,
    const float* __restrict__ kin,
    const float* __restrict__ vin,
    const float* __restrict__ kc,
    const float* __restrict__ vc,
    const int*  __restrict__ slot_mapping,
    const int*  __restrict__ active_slots,
    const int*  __restrict__ context_lens,
    float* __restrict__ part_o,
    float* __restrict__ part_ml)
{
    constexpr int NSPLIT = LMAX / CHUNK;
    const int tid   = threadIdx.x;            // 0..63
    const int split = blockIdx.x % NSPLIT;
    const int h     = (blockIdx.x / NSPLIT) % HKV;
    const int b     = blockIdx.x / (NSPLIT * HKV);

    const int ctx   = context_lens[b];
    const int start = split * CHUNK;
    int nvalid = ctx - start;
    if (nvalid > CHUNK) nvalid = CHUNK;

    const size_t pbase = ((size_t)(b * HKV + h) * NSPLIT + split) * G;

    if (nvalid <= 0) {
        if (tid < G * 2) part_ml[pbase * 2 + tid] = (tid & 1) ? 0.f : -FLT_MAX;
        return;
    }

    __shared__ const float* kp[CHUNK];     // wave-private (1 wave/block)
    __shared__ const float* vp[CHUNK];
    __shared__ float  red[8][G][D];        // 16KB group-combine buffer
    __shared__ float2 mlred[8][G];

    // ---- resolve slot -> row pointers (slot_mapping uniform -> scalar loads)
    int smv[16];
#pragma unroll
    for (int j = 0; j < 16; ++j) smv[j] = slot_mapping[j];
    for (int li = tid; li < nvalid; li += 64) {
        const int s = active_slots[b * LMAX + start + li];
        int ov = -1;
#pragma unroll
        for (int j = 0; j < 16; ++j)
            if (smv[j] == s) ov = j;
        kp[li] = (ov >= 0) ? kin + ((size_t)ov * HKV + h) * D : kc + ((size_t)s * HKV + h) * D;
        vp[li] = (ov >= 0) ? vin + ((size_t)ov * HKV + h) * D : vc + ((size_t)s * HKV + h) * D;
    }

    const int grp   = tid >> 3;   // 0..7 : group (owns rows it*8+grp)
    const int lane8 = tid & 7;    // d-chunk within row

    // q fragments (pre-scaled): qv[g][j] = d-floats [j*32+lane8*4 ..+4)
    float4 qv[G][4];
#pragma unroll
    for (int g = 0; g < G; ++g) {
        const float* qp = q + ((size_t)(b * H + h * G + g)) * D;
#pragma unroll
        for (int j = 0; j < 4; ++j) {
            float4 t = *(const float4*)(qp + j * 32 + lane8 * 4);
            qv[g][j] = make_float4(t.x * SCALE, t.y * SCALE, t.z * SCALE, t.w * SCALE);
        }
    }

    // running state per head (replicated across the group's 8 lanes for m,l;
    // O is per-lane d-chunks). Static indexing only (rule #20).
    float m0 = -1e30f, m1 = -1e30f, m2 = -1e30f, m3 = -1e30f;
    float l0 = 0.f, l1 = 0.f, l2 = 0.f, l3 = 0.f;
    float4 o0[4] = {}, o1[4] = {}, o2[4] = {}, o3[4] = {};

    constexpr int ITERS = CHUNK / 8;
#pragma unroll 2
    for (int it = 0; it < ITERS; ++it) {
        const int r  = it * 8 + grp;
        const int rl = (r < nvalid) ? r : nvalid - 1;   // branchless clamp
        const float* kb = kp[rl];
        const float* vb = vp[rl];
        float4 kv[4], vv[4];
#pragma unroll
        for (int j = 0; j < 4; ++j) kv[j] = *(const float4*)(kb + j * 32 + lane8 * 4);
#pragma unroll
        for (int j = 0; j < 4; ++j) vv[j] = *(const float4*)(vb + j * 32 + lane8 * 4);

        float pd0 = 0.f, pd1 = 0.f, pd2 = 0.f, pd3 = 0.f;
#pragma unroll
        for (int j = 0; j < 4; ++j) {
            pd0 += kv[j].x * qv[0][j].x + kv[j].y * qv[0][j].y + kv[j].z * qv[0][j].z + kv[j].w * qv[0][j].w;
            pd1 += kv[j].x * qv[1][j].x + kv[j].y * qv[1][j].y + kv[j].z * qv[1][j].z + kv[j].w * qv[1][j].w;
            pd2 += kv[j].x * qv[2][j].x + kv[j].y * qv[2][j].y + kv[j].z * qv[2][j].z + kv[j].w * qv[2][j].w;
            pd3 += kv[j].x * qv[3][j].x + kv[j].y * qv[3][j].y + kv[j].z * qv[3][j].z + kv[j].w * qv[3][j].w;
        }
#pragma unroll
        for (int msk = 1; msk < 8; msk <<= 1) {
            pd0 += __shfl_xor(pd0, msk, 8);
            pd1 += __shfl_xor(pd1, msk, 8);
            pd2 += __shfl_xor(pd2, msk, 8);
            pd3 += __shfl_xor(pd3, msk, 8);
        }

        const bool valid = (r < nvalid);
        const float s0 = valid ? pd0 : -1e30f;
        const float s1 = valid ? pd1 : -1e30f;
        const float s2 = valid ? pd2 : -1e30f;
        const float s3 = valid ? pd3 : -1e30f;

        // defer-max rescale (rare; first valid row takes it with sc==0)
        if (s0 > m0 + THR) {
            const float sc = __expf(m0 - s0); l0 *= sc; m0 = s0;
#pragma unroll
            for (int j = 0; j < 4; ++j) { o0[j].x *= sc; o0[j].y *= sc; o0[j].z *= sc; o0[j].w *= sc; }
        }
        if (s1 > m1 + THR) {
            const float sc = __expf(m1 - s1); l1 *= sc; m1 = s1;
#pragma unroll
            for (int j = 0; j < 4; ++j) { o1[j].x *= sc; o1[j].y *= sc; o1[j].z *= sc; o1[j].w *= sc; }
        }
        if (s2 > m2 + THR) {
            const float sc = __expf(m2 - s2); l2 *= sc; m2 = s2;
#pragma unroll
            for (int j = 0; j < 4; ++j) { o2[j].x *= sc; o2[j].y *= sc; o2[j].z *= sc; o2[j].w *= sc; }
        }
        if (s3 > m3 + THR) {
            const float sc = __expf(m3 - s3); l3 *= sc; m3 = s3;
#pragma unroll
            for (int j = 0; j < 4; ++j) { o3[j].x *= sc; o3[j].y *= sc; o3[j].z *= sc; o3[j].w *= sc; }
        }

        const float p0 = __expf(s0 - m0);   // 0 for invalid rows (m real) or
        const float p1 = __expf(s1 - m1);   // zero-weighted later (group empty)
        const float p2 = __expf(s2 - m2);
        const float p3 = __expf(s3 - m3);
        l0 += p0; l1 += p1; l2 += p2; l3 += p3;
#pragma unroll
        for (int j = 0; j < 4; ++j) {
            o0[j].x += p0 * vv[j].x; o0[j].y += p0 * vv[j].y; o0[j].z += p0 * vv[j].z; o0[j].w += p0 * vv[j].w;
            o1[j].x += p1 * vv[j].x; o1[j].y += p1 * vv[j].y; o1[j].z += p1 * vv[j].z; o1[j].w += p1 * vv[j].w;
            o2[j].x += p2 * vv[j].x; o2[j].y += p2 * vv[j].y; o2[j].z += p2 * vv[j].z; o2[j].w += p2 * vv[j].w;
            o3[j].x += p3 * vv[j].x; o3[j].y += p3 * vv[j].y; o3[j].z += p3 * vv[j].z; o3[j].w += p3 * vv[j].w;
        }
    }

    // ---- epilogue: LSE-merge the 8 groups (single wave; lgkmcnt only)
#pragma unroll
    for (int j = 0; j < 4; ++j) {
        *(float4*)&red[grp][0][j * 32 + lane8 * 4] = o0[j];
        *(float4*)&red[grp][1][j * 32 + lane8 * 4] = o1[j];
        *(float4*)&red[grp][2][j * 32 + lane8 * 4] = o2[j];
        *(float4*)&red[grp][3][j * 32 + lane8 * 4] = o3[j];
    }
    if (lane8 == 0) {
        mlred[grp][0] = make_float2(m0, l0);
        mlred[grp][1] = make_float2(m1, l1);
        mlred[grp][2] = make_float2(m2, l2);
        mlred[grp][3] = make_float2(m3, l3);
    }
    __syncthreads();   // 1 wave: compiles to waitcnt; ordering only

#pragma unroll
    for (int g = 0; g < G; ++g) {
        float Mg = -1e30f;
#pragma unroll
        for (int gr = 0; gr < 8; ++gr) Mg = fmaxf(Mg, mlred[gr][g].x);
        float Lg = 0.f, acc0 = 0.f, acc1 = 0.f;
#pragma unroll
        for (int gr = 0; gr < 8; ++gr) {
            const float2 ml = mlred[gr][g];
            const float w = __expf(ml.x - Mg);   // empty group: exp(-1e30-Mg)=0
            Lg += ml.y * w;
            acc0 += red[gr][g][tid]      * w;
            acc1 += red[gr][g][tid + 64] * w;
        }
        part_o[(pbase + g) * D + tid]      = acc0;
        part_o[(pbase + g) * D + tid + 64] = acc1;
        if (tid == 0) {
            part_ml[(pbase + g) * 2 + 0] = Mg;
            part_ml[(pbase + g) * 2 + 1] = Lg;
        }
    }
}

// Kernel 2: merge nsplit partials per (b, h, g); 2-way split-parallel.
__global__ __launch_bounds__(256) void attn_reduce(
    const float* __restrict__ part_o,
    const float* __restrict__ part_ml,
    float* __restrict__ out,
    int nsplit)
{
    const int g = blockIdx.x & 3;
    const int h = (blockIdx.x >> 2) & 7;
    const int b = blockIdx.x >> 5;
    const int d  = threadIdx.x & 127;
    const int sp = threadIdx.x >> 7;

    __shared__ float mlds[64], llds[64];
    __shared__ float red[128];
    __shared__ float lred;
    const size_t base = (size_t)(b * HKV + h) * nsplit;

    for (int s = threadIdx.x; s < nsplit; s += 256) {
        mlds[s] = part_ml[((base + s) * G + g) * 2 + 0];
        llds[s] = part_ml[((base + s) * G + g) * 2 + 1];
    }
    __syncthreads();

    float M = -FLT_MAX;
    for (int s = 0; s < nsplit; ++s)
        if (llds[s] > 0.f) M = fmaxf(M, mlds[s]);

    float L = 0.f, acc = 0.f;
    for (int s = sp; s < nsplit; s += 2) {
        const float l = llds[s];
        if (l > 0.f) {
            const float e = __expf(mlds[s] - M);
            L += l * e;
            acc += e * part_o[((base + s) * G + g) * D + d];
        }
    }
    if (sp == 1) {
        red[d] = acc;
        if (d == 0) lred = L;
    }
    __syncthreads();
    if (sp == 0) {
        acc += red[d];
        L   += lred;
        out[((size_t)(b * H) + h * G + g) * D + d] = acc / (L > 0.f ? L : 1.f);
    }
}

extern "C" void kernel_launch(void* const* d_in, const int* in_sizes, int n_in,
                              void* d_out, int out_size, void* d_ws, size_t ws_size,
                              hipStream_t stream) {
    const float* q  = (const float*)d_in[0];
    const float* k  = (const float*)d_in[1];
    const float* v  = (const float*)d_in[2];
    const float* kc = (const float*)d_in[3];
    const float* vc = (const float*)d_in[4];
    const int* slot_mapping = (const int*)d_in[5];
    const int* active_slots = (const int*)d_in[6];
    const int* context_lens = (const int*)d_in[7];
    float* out = (float*)d_out;

    const size_t perSplit = (size_t)B * HKV * (G * D + G * 2) * sizeof(float);
    int nsplit = 8;
    if (ws_size >= 32 * perSplit)      nsplit = 32;
    else if (ws_size >= 16 * perSplit) nsplit = 16;

    float* part_o  = (float*)d_ws;
    float* part_ml = part_o + (size_t)B * HKV * nsplit * G * D;

    if (nsplit == 32) {
        attn_partial<64><<<B * HKV * 32, 64, 0, stream>>>(
            q, k, v, kc, vc, slot_mapping, active_slots, context_lens, part_o, part_ml);
    } else if (nsplit == 16) {
        attn_partial<128><<<B * HKV * 16, 64, 0, stream>>>(
            q, k, v, kc, vc, slot_mapping, active_slots, context_lens, part_o, part_ml);
    } else {
        attn_partial<256><<<B * HKV * 8, 64, 0, stream>>>(
            q, k, v, kc, vc, slot_mapping, active_slots, context_lens, part_o, part_ml);
    }
    attn_reduce<<<B * HKV * G, 256, 0, stream>>>(part_o, part_ml, out, nsplit);
}